// Round 20
// baseline (31.674 us; speedup 1.0000x reference)
//
#include <hip/hip_runtime.h>

#define B      512
#define NBG    10000
#define F      32
#define H      128
#define PTS    20          // points per block
#define NPG    500         // NPG*PTS == NBG
#define RB     2           // batch rows per MLP block
#define MLPBLK (B / RB)    // 256

// quad (4-lane) sum via DPP quad_perm: xor1 [1,0,3,2]=0xB1, xor2 [2,3,0,1]=0x4E
__device__ __forceinline__ float qsum(float v) {
    int a = __builtin_amdgcn_update_dpp(0, __float_as_int(v), 0xB1, 0xF, 0xF, true);
    float v1 = v + __int_as_float(a);
    int b = __builtin_amdgcn_update_dpp(0, __float_as_int(v1), 0x4E, 0xF, 0xF, true);
    return v1 + __int_as_float(b);
}
// one xor-1 round: combines lane pairs (0,1) and (2,3)
__device__ __forceinline__ float psum1(float v) {
    int a = __builtin_amdgcn_update_dpp(0, __float_as_int(v), 0xB1, 0xF, 0xF, true);
    return v + __int_as_float(a);
}

// ---------------- Kernel A: MLP -> babsR[b][f] (row-major), RB=2 for 256 blocks ----------------
__global__ __launch_bounds__(128) void prep_kernel(
    const float* __restrict__ X,
    const float* __restrict__ W0, const float* __restrict__ b0,
    const float* __restrict__ W1, const float* __restrict__ b1,
    const float* __restrict__ Wout, const float* __restrict__ bout,
    float* __restrict__ babsR)
{
    __shared__ __align__(16) float xr[RB * F];
    __shared__ __align__(16) float h0[RB * H];
    __shared__ __align__(16) float h1[RB * H];
    const int t  = threadIdx.x;
    const int r0 = blockIdx.x * RB;

    for (int i = t; i < RB * F; i += 128) {
        int r = i >> 5, f = i & 31;
        xr[r * F + f] = X[(r0 + r) * F + f];
    }
    __syncthreads();

    float acc[RB];
    #pragma unroll
    for (int r = 0; r < RB; ++r) acc[r] = b0[t];
    #pragma unroll
    for (int f4 = 0; f4 < F / 4; ++f4) {
        float wa = W0[(4*f4+0)*H + t];
        float wb = W0[(4*f4+1)*H + t];
        float wc = W0[(4*f4+2)*H + t];
        float wd = W0[(4*f4+3)*H + t];
        #pragma unroll
        for (int r = 0; r < RB; ++r) {
            float4 xv = *(const float4*)&xr[r * F + 4*f4];
            acc[r] += xv.x*wa + xv.y*wb + xv.z*wc + xv.w*wd;
        }
    }
    #pragma unroll
    for (int r = 0; r < RB; ++r) h0[r * H + t] = fmaxf(acc[r], 0.f);
    __syncthreads();

    #pragma unroll
    for (int r = 0; r < RB; ++r) acc[r] = b1[t];
    #pragma unroll 8
    for (int j4 = 0; j4 < H / 4; ++j4) {
        float wa = W1[(4*j4+0)*H + t];
        float wb = W1[(4*j4+1)*H + t];
        float wc = W1[(4*j4+2)*H + t];
        float wd = W1[(4*j4+3)*H + t];
        #pragma unroll
        for (int r = 0; r < RB; ++r) {
            float4 hv = *(const float4*)&h0[r * H + 4*j4];
            acc[r] += hv.x*wa + hv.y*wb + hv.z*wc + hv.w*wd;
        }
    }
    #pragma unroll
    for (int r = 0; r < RB; ++r) h1[r * H + t] = fmaxf(acc[r], 0.f);
    __syncthreads();

    for (int i = t; i < RB * F; i += 128) {
        int r = i >> 5, f = i & 31;
        float a = bout[f];
        #pragma unroll 8
        for (int j4 = 0; j4 < H / 4; ++j4) {
            float4 hv = *(const float4*)&h1[r * H + 4*j4];
            a += hv.x*Wout[(4*j4+0)*F + f] + hv.y*Wout[(4*j4+1)*F + f]
               + hv.z*Wout[(4*j4+2)*F + f] + hv.w*Wout[(4*j4+3)*F + f];
        }
        babsR[(r0 + r) * F + f] = fabsf(a);
    }
}

// ---------------- Kernel B: NW partial sums — zero-LDS variant ----------------
// r19 body with the LDS tile deleted: each lane reads its fg-slice of the
// point-pair DIRECTLY from global xbg. Per wave-instruction the 64 lanes hit
// only 4 distinct 16B addresses spanning 128 contiguous bytes (2 cache lines)
// -> full TA coalescing, L2-resident (xbg = 1.28 MB). Removes staging + 40
// ds_read_b128/wave (the ~6.2us LDS-pipe term); adds 40 L2-hit dwordx4 loads
// (~2us VMEM). No __syncthreads, no shared memory at all.
__global__ __launch_bounds__(256) void nw_partial(
    const float* __restrict__ X,       // [B][F] row-major
    const float* __restrict__ babsR,   // [B][F] row-major
    const float* __restrict__ xbg,
    const float* __restrict__ ybg,
    float* __restrict__ psw,
    float* __restrict__ pswy)
{
    const int tid = threadIdx.x;
    const int fg  = tid & 3;
    const int bs  = tid >> 2;                // 0..63
    const int b0i = blockIdx.y * 128 + bs;
    const int b1i = b0i + 64;
    const int n0  = blockIdx.x * PTS;

    const float4 xqA0 = *(const float4*)&X[b0i * F + fg * 8];
    const float4 xqB0 = *(const float4*)&X[b0i * F + fg * 8 + 4];
    const float4 xqA1 = *(const float4*)&X[b1i * F + fg * 8];
    const float4 xqB1 = *(const float4*)&X[b1i * F + fg * 8 + 4];
    const float4 bvA0 = *(const float4*)&babsR[b0i * F + fg * 8];
    const float4 bvB0 = *(const float4*)&babsR[b0i * F + fg * 8 + 4];
    const float4 bvA1 = *(const float4*)&babsR[b1i * F + fg * 8];
    const float4 bvB1 = *(const float4*)&babsR[b1i * F + fg * 8 + 4];

    // lane's slice base: float4 index (n0*8 + fg*2); per jp: +jp*16 (p0), +8 (p1)
    const float4* __restrict__ xr4 = (const float4*)(xbg + n0 * F) + fg * 2;

    float swp = 0.f, swyp = 0.f;      // this lane's (point-parity, row) partial

    #pragma unroll 2
    for (int jq = 0; jq < PTS / 4; ++jq) {
        // block-uniform address -> scalar load (SGPR)
        const float4 yv = *(const float4*)&ybg[n0 + jq * 4];
        #pragma unroll
        for (int jj = 0; jj < 2; ++jj) {
            const int jp = jq * 2 + jj;
            const float4 pA0 = xr4[jp * 16 + 0];   // p0, feats fg*8..+3
            const float4 pA1 = xr4[jp * 16 + 1];   // p0, feats fg*8+4..+7
            const float4 pB0 = xr4[jp * 16 + 8];   // p1, feats fg*8..+3
            const float4 pB1 = xr4[jp * 16 + 9];   // p1, feats fg*8+4..+7

            float d00 = 0.f, d10 = 0.f, d01 = 0.f, d11 = 0.f;  // d[pt][row]
            d00 += bvA0.x * fabsf(xqA0.x - pA0.x);
            d00 += bvA0.y * fabsf(xqA0.y - pA0.y);
            d00 += bvA0.z * fabsf(xqA0.z - pA0.z);
            d00 += bvA0.w * fabsf(xqA0.w - pA0.w);
            d00 += bvB0.x * fabsf(xqB0.x - pA1.x);
            d00 += bvB0.y * fabsf(xqB0.y - pA1.y);
            d00 += bvB0.z * fabsf(xqB0.z - pA1.z);
            d00 += bvB0.w * fabsf(xqB0.w - pA1.w);

            d10 += bvA0.x * fabsf(xqA0.x - pB0.x);
            d10 += bvA0.y * fabsf(xqA0.y - pB0.y);
            d10 += bvA0.z * fabsf(xqA0.z - pB0.z);
            d10 += bvA0.w * fabsf(xqA0.w - pB0.w);
            d10 += bvB0.x * fabsf(xqB0.x - pB1.x);
            d10 += bvB0.y * fabsf(xqB0.y - pB1.y);
            d10 += bvB0.z * fabsf(xqB0.z - pB1.z);
            d10 += bvB0.w * fabsf(xqB0.w - pB1.w);

            d01 += bvA1.x * fabsf(xqA1.x - pA0.x);
            d01 += bvA1.y * fabsf(xqA1.y - pA0.y);
            d01 += bvA1.z * fabsf(xqA1.z - pA0.z);
            d01 += bvA1.w * fabsf(xqA1.w - pA0.w);
            d01 += bvB1.x * fabsf(xqB1.x - pA1.x);
            d01 += bvB1.y * fabsf(xqB1.y - pA1.y);
            d01 += bvB1.z * fabsf(xqB1.z - pA1.z);
            d01 += bvB1.w * fabsf(xqB1.w - pA1.w);

            d11 += bvA1.x * fabsf(xqA1.x - pB0.x);
            d11 += bvA1.y * fabsf(xqA1.y - pB0.y);
            d11 += bvA1.z * fabsf(xqA1.z - pB0.z);
            d11 += bvA1.w * fabsf(xqA1.w - pB0.w);
            d11 += bvB1.x * fabsf(xqB1.x - pB1.x);
            d11 += bvB1.y * fabsf(xqB1.y - pB1.y);
            d11 += bvB1.z * fabsf(xqB1.z - pB1.z);
            d11 += bvB1.w * fabsf(xqB1.w - pB1.w);

            // full quad-sums (every lane ends with all four totals)
            d00 = qsum(d00); d10 = qsum(d10);
            d01 = qsum(d01); d11 = qsum(d11);

            // lane fg handles combo fg: 0=(p0,r0) 1=(p1,r0) 2=(p0,r1) 3=(p1,r1)
            float dA   = (fg & 1) ? d10 : d00;
            float dB   = (fg & 1) ? d11 : d01;
            float dsel = (fg & 2) ? dB : dA;
            float ysel = (fg & 1) ? (jj ? yv.w : yv.y) : (jj ? yv.z : yv.x);
            float w = __expf(-dsel);
            swp  += w;
            swyp += w * ysel;
        }
    }

    // combine point-parity partials: lanes (0,1) -> row0, lanes (2,3) -> row1
    swp  = psum1(swp);
    swyp = psum1(swyp);

    if (fg == 0) {
        psw [blockIdx.x * B + b0i] = swp;
        pswy[blockIdx.x * B + b0i] = swyp;
    } else if (fg == 2) {
        psw [blockIdx.x * B + b1i] = swp;
        pswy[blockIdx.x * B + b1i] = swyp;
    }
}

// ---------------- Kernel C: combine partials, normalize ----------------
__global__ __launch_bounds__(64) void nw_final(
    const float* __restrict__ psw,
    const float* __restrict__ pswy,
    float* __restrict__ out)
{
    const int b = blockIdx.x;
    const int t = threadIdx.x;

    float sw = 0.f, swy = 0.f;
    for (int c = t; c < NPG; c += 64) {
        sw  += psw [c * B + b];
        swy += pswy[c * B + b];
    }
    #pragma unroll
    for (int off = 32; off > 0; off >>= 1) {
        sw  += __shfl_down(sw,  off);
        swy += __shfl_down(swy, off);
    }
    if (t == 0) out[b] = swy / sw;
}

extern "C" void kernel_launch(void* const* d_in, const int* in_sizes, int n_in,
                              void* d_out, int out_size, void* d_ws, size_t ws_size,
                              hipStream_t stream)
{
    const float* X    = (const float*)d_in[0];
    const float* xbg  = (const float*)d_in[1];
    const float* ybg  = (const float*)d_in[2];
    const float* W0   = (const float*)d_in[3];
    const float* b0   = (const float*)d_in[4];
    const float* W1   = (const float*)d_in[5];
    const float* b1   = (const float*)d_in[6];
    const float* Wout = (const float*)d_in[7];
    const float* bout = (const float*)d_in[8];
    float* out = (float*)d_out;

    float* babsR = (float*)d_ws;              // B*F
    float* psw   = babsR + B * F;             // NPG*B (1 MB)
    float* pswy  = psw + NPG * B;             // NPG*B (1 MB)

    prep_kernel<<<MLPBLK, 128, 0, stream>>>(X, W0, b0, W1, b1, Wout, bout, babsR);
    nw_partial<<<dim3(NPG, 4), 256, 0, stream>>>(X, babsR, xbg, ybg, psw, pswy);
    nw_final<<<B, 64, 0, stream>>>(psw, pswy, out);
}

// Round 21
// 29.360 us; speedup vs baseline: 1.0788x; 1.0788x over previous
//
#include <hip/hip_runtime.h>

#define B      512
#define NBG    10000
#define F      32
#define H      128
#define PTS    20          // points per block
#define NPG    500         // NPG*PTS == NBG
#define RB     2           // batch rows per MLP block
#define MLPBLK (B / RB)    // 256

// quad (4-lane) sum via DPP quad_perm: xor1 [1,0,3,2]=0xB1, xor2 [2,3,0,1]=0x4E
__device__ __forceinline__ float qsum(float v) {
    int a = __builtin_amdgcn_update_dpp(0, __float_as_int(v), 0xB1, 0xF, 0xF, true);
    float v1 = v + __int_as_float(a);
    int b = __builtin_amdgcn_update_dpp(0, __float_as_int(v1), 0x4E, 0xF, 0xF, true);
    return v1 + __int_as_float(b);
}
// one xor-1 round: combines lane pairs (0,1) and (2,3)
__device__ __forceinline__ float psum1(float v) {
    int a = __builtin_amdgcn_update_dpp(0, __float_as_int(v), 0xB1, 0xF, 0xF, true);
    return v + __int_as_float(a);
}

// ---------------- Kernel A: MLP -> babsR[b][f] (row-major), RB=2 / 256 blocks ----------------
__global__ __launch_bounds__(128) void prep_kernel(
    const float* __restrict__ X,
    const float* __restrict__ W0, const float* __restrict__ b0,
    const float* __restrict__ W1, const float* __restrict__ b1,
    const float* __restrict__ Wout, const float* __restrict__ bout,
    float* __restrict__ babsR)
{
    __shared__ __align__(16) float xr[RB * F];
    __shared__ __align__(16) float h0[RB * H];
    __shared__ __align__(16) float h1[RB * H];
    const int t  = threadIdx.x;
    const int r0 = blockIdx.x * RB;

    for (int i = t; i < RB * F; i += 128) {
        int r = i >> 5, f = i & 31;
        xr[r * F + f] = X[(r0 + r) * F + f];
    }
    __syncthreads();

    float acc[RB];
    #pragma unroll
    for (int r = 0; r < RB; ++r) acc[r] = b0[t];
    #pragma unroll
    for (int f4 = 0; f4 < F / 4; ++f4) {
        float wa = W0[(4*f4+0)*H + t];
        float wb = W0[(4*f4+1)*H + t];
        float wc = W0[(4*f4+2)*H + t];
        float wd = W0[(4*f4+3)*H + t];
        #pragma unroll
        for (int r = 0; r < RB; ++r) {
            float4 xv = *(const float4*)&xr[r * F + 4*f4];
            acc[r] += xv.x*wa + xv.y*wb + xv.z*wc + xv.w*wd;
        }
    }
    #pragma unroll
    for (int r = 0; r < RB; ++r) h0[r * H + t] = fmaxf(acc[r], 0.f);
    __syncthreads();

    #pragma unroll
    for (int r = 0; r < RB; ++r) acc[r] = b1[t];
    #pragma unroll 8
    for (int j4 = 0; j4 < H / 4; ++j4) {
        float wa = W1[(4*j4+0)*H + t];
        float wb = W1[(4*j4+1)*H + t];
        float wc = W1[(4*j4+2)*H + t];
        float wd = W1[(4*j4+3)*H + t];
        #pragma unroll
        for (int r = 0; r < RB; ++r) {
            float4 hv = *(const float4*)&h0[r * H + 4*j4];
            acc[r] += hv.x*wa + hv.y*wb + hv.z*wc + hv.w*wd;
        }
    }
    #pragma unroll
    for (int r = 0; r < RB; ++r) h1[r * H + t] = fmaxf(acc[r], 0.f);
    __syncthreads();

    for (int i = t; i < RB * F; i += 128) {
        int r = i >> 5, f = i & 31;
        float a = bout[f];
        #pragma unroll 8
        for (int j4 = 0; j4 < H / 4; ++j4) {
            float4 hv = *(const float4*)&h1[r * H + 4*j4];
            a += hv.x*Wout[(4*j4+0)*F + f] + hv.y*Wout[(4*j4+1)*F + f]
               + hv.z*Wout[(4*j4+2)*F + f] + hv.w*Wout[(4*j4+3)*F + f];
        }
        babsR[(r0 + r) * F + f] = fabsf(a);
    }
}

// ---------------- Kernel B: NW partial sums (r19 body — best measured) ----------------
// LDS point-pair interleaved tile (1 ds_read_b128 = 2 feats x 2 pts), lane =
// (bs, fg-quad) owning 8 feats x 2 rows, DPP quad reduce, exp-dedup (1 exp
// per lane per point-pair), y via uniform s_load. 2000 blocks x 4 waves =
// 8000 waves (31/CU). Measured 30.2us total; r20's zero-LDS variant was
// WORSE (+1.5us) -> LDS broadcast beats direct-global same-address reads.
__global__ __launch_bounds__(256) void nw_partial(
    const float* __restrict__ X,       // [B][F] row-major
    const float* __restrict__ babsR,   // [B][F] row-major
    const float* __restrict__ xbg,
    const float* __restrict__ ybg,
    float* __restrict__ psw,
    float* __restrict__ pswy)
{
    __shared__ __align__(16) float ttp[PTS / 2 * F * 2];  // [10][32][2] = 640
    const int tid = threadIdx.x;
    const int fg  = tid & 3;
    const int bs  = tid >> 2;                // 0..63
    const int b0i = blockIdx.y * 128 + bs;
    const int b1i = b0i + 64;
    const int n0  = blockIdx.x * PTS;

    for (int i = tid; i < PTS * F; i += 256) {
        int nr = i >> 5, f = i & 31;
        ttp[(nr >> 1) * 64 + f * 2 + (nr & 1)] = xbg[n0 * F + i];
    }

    const float4 xqA0 = *(const float4*)&X[b0i * F + fg * 8];
    const float4 xqB0 = *(const float4*)&X[b0i * F + fg * 8 + 4];
    const float4 xqA1 = *(const float4*)&X[b1i * F + fg * 8];
    const float4 xqB1 = *(const float4*)&X[b1i * F + fg * 8 + 4];
    const float4 bvA0 = *(const float4*)&babsR[b0i * F + fg * 8];
    const float4 bvB0 = *(const float4*)&babsR[b0i * F + fg * 8 + 4];
    const float4 bvA1 = *(const float4*)&babsR[b1i * F + fg * 8];
    const float4 bvB1 = *(const float4*)&babsR[b1i * F + fg * 8 + 4];
    __syncthreads();

    const float4* t4 = (const float4*)ttp;
    float swp = 0.f, swyp = 0.f;      // this lane's (point-parity, row) partial

    #pragma unroll
    for (int jq = 0; jq < PTS / 4; ++jq) {
        // block-uniform address -> scalar load (SGPR), no LDS staging
        const float4 yv = *(const float4*)&ybg[n0 + jq * 4];
        #pragma unroll
        for (int jj = 0; jj < 2; ++jj) {
            const int jp = jq * 2 + jj;
            const int base = jp * 16 + fg * 4;
            float d00 = 0.f, d10 = 0.f, d01 = 0.f, d11 = 0.f;  // d[pt][row]
            {
                float4 v0 = t4[base + 0];
                float4 v1 = t4[base + 1];
                d00 += bvA0.x * fabsf(xqA0.x - v0.x);
                d10 += bvA0.x * fabsf(xqA0.x - v0.y);
                d01 += bvA1.x * fabsf(xqA1.x - v0.x);
                d11 += bvA1.x * fabsf(xqA1.x - v0.y);
                d00 += bvA0.y * fabsf(xqA0.y - v0.z);
                d10 += bvA0.y * fabsf(xqA0.y - v0.w);
                d01 += bvA1.y * fabsf(xqA1.y - v0.z);
                d11 += bvA1.y * fabsf(xqA1.y - v0.w);
                d00 += bvA0.z * fabsf(xqA0.z - v1.x);
                d10 += bvA0.z * fabsf(xqA0.z - v1.y);
                d01 += bvA1.z * fabsf(xqA1.z - v1.x);
                d11 += bvA1.z * fabsf(xqA1.z - v1.y);
                d00 += bvA0.w * fabsf(xqA0.w - v1.z);
                d10 += bvA0.w * fabsf(xqA0.w - v1.w);
                d01 += bvA1.w * fabsf(xqA1.w - v1.z);
                d11 += bvA1.w * fabsf(xqA1.w - v1.w);
            }
            {
                float4 v2 = t4[base + 2];
                float4 v3 = t4[base + 3];
                d00 += bvB0.x * fabsf(xqB0.x - v2.x);
                d10 += bvB0.x * fabsf(xqB0.x - v2.y);
                d01 += bvB1.x * fabsf(xqB1.x - v2.x);
                d11 += bvB1.x * fabsf(xqB1.x - v2.y);
                d00 += bvB0.y * fabsf(xqB0.y - v2.z);
                d10 += bvB0.y * fabsf(xqB0.y - v2.w);
                d01 += bvB1.y * fabsf(xqB1.y - v2.z);
                d11 += bvB1.y * fabsf(xqB1.y - v2.w);
                d00 += bvB0.z * fabsf(xqB0.z - v3.x);
                d10 += bvB0.z * fabsf(xqB0.z - v3.y);
                d01 += bvB1.z * fabsf(xqB1.z - v3.x);
                d11 += bvB1.z * fabsf(xqB1.z - v3.y);
                d00 += bvB0.w * fabsf(xqB0.w - v3.z);
                d10 += bvB0.w * fabsf(xqB0.w - v3.w);
                d01 += bvB1.w * fabsf(xqB1.w - v3.z);
                d11 += bvB1.w * fabsf(xqB1.w - v3.w);
            }
            // full quad-sums (every lane ends with all four totals)
            d00 = qsum(d00); d10 = qsum(d10);
            d01 = qsum(d01); d11 = qsum(d11);

            // lane fg handles combo fg: 0=(p0,r0) 1=(p1,r0) 2=(p0,r1) 3=(p1,r1)
            float dA   = (fg & 1) ? d10 : d00;
            float dB   = (fg & 1) ? d11 : d01;
            float dsel = (fg & 2) ? dB : dA;
            float ysel = (fg & 1) ? (jj ? yv.w : yv.y) : (jj ? yv.z : yv.x);
            float w = __expf(-dsel);
            swp  += w;
            swyp += w * ysel;
        }
    }

    // combine point-parity partials: lanes (0,1) -> row0, lanes (2,3) -> row1
    swp  = psum1(swp);
    swyp = psum1(swyp);

    if (fg == 0) {
        psw [blockIdx.x * B + b0i] = swp;
        pswy[blockIdx.x * B + b0i] = swyp;
    } else if (fg == 2) {
        psw [blockIdx.x * B + b1i] = swp;
        pswy[blockIdx.x * B + b1i] = swyp;
    }
}

// ---------------- Kernel C: combine partials, normalize ----------------
__global__ __launch_bounds__(64) void nw_final(
    const float* __restrict__ psw,
    const float* __restrict__ pswy,
    float* __restrict__ out)
{
    const int b = blockIdx.x;
    const int t = threadIdx.x;

    float sw = 0.f, swy = 0.f;
    for (int c = t; c < NPG; c += 64) {
        sw  += psw [c * B + b];
        swy += pswy[c * B + b];
    }
    #pragma unroll
    for (int off = 32; off > 0; off >>= 1) {
        sw  += __shfl_down(sw,  off);
        swy += __shfl_down(swy, off);
    }
    if (t == 0) out[b] = swy / sw;
}

extern "C" void kernel_launch(void* const* d_in, const int* in_sizes, int n_in,
                              void* d_out, int out_size, void* d_ws, size_t ws_size,
                              hipStream_t stream)
{
    const float* X    = (const float*)d_in[0];
    const float* xbg  = (const float*)d_in[1];
    const float* ybg  = (const float*)d_in[2];
    const float* W0   = (const float*)d_in[3];
    const float* b0   = (const float*)d_in[4];
    const float* W1   = (const float*)d_in[5];
    const float* b1   = (const float*)d_in[6];
    const float* Wout = (const float*)d_in[7];
    const float* bout = (const float*)d_in[8];
    float* out = (float*)d_out;

    float* babsR = (float*)d_ws;              // B*F
    float* psw   = babsR + B * F;             // NPG*B (1 MB)
    float* pswy  = psw + NPG * B;             // NPG*B (1 MB)

    prep_kernel<<<MLPBLK, 128, 0, stream>>>(X, W0, b0, W1, b1, Wout, bout, babsR);
    nw_partial<<<dim3(NPG, 4), 256, 0, stream>>>(X, babsR, xbg, ybg, psw, pswy);
    nw_final<<<B, 64, 0, stream>>>(psw, pswy, out);
}